// Round 3
// baseline (126.466 us; speedup 1.0000x reference)
//
#include <hip/hip_runtime.h>

typedef float f4 __attribute__((ext_vector_type(4)));

#define BB   16
#define NN   512
#define DIN  256
#define COUT 32
#define CCS  48
#define HH   256
#define WWG  256
#define HW   (HH * WWG)          // 65536 = 1<<16
#define CTOT (CCS + COUT)        // 80

// ---------------------------------------------------------------------------
// Fused: blocks [0,1024): proj = emb·W + b (8 entity-rows/block, W in LDS).
// blocks [1024,1056): cellmap[b,h,w] = atomicMax(flat entity index i).
// cellmap must be pre-set to -1 (async memset 0xFF). For a fixed cell all
// contenders share b, so max(i) == max(n) == last-write-wins.
// ---------------------------------------------------------------------------
__global__ __launch_bounds__(256) void k_projwin(
        const float* __restrict__ emb, const float* __restrict__ Wm,
        const float* __restrict__ bias, const int* __restrict__ loc,
        float* __restrict__ proj, int* __restrict__ cellmap) {
    __shared__ float Wl[DIN * COUT];
    int tid = threadIdx.x;
    if (blockIdx.x < 1024) {
        for (int i = tid; i < DIN * COUT; i += 256) Wl[i] = Wm[i];
        __syncthreads();
        int c = tid & 31;
        int r = tid >> 5;                        // 0..7
        int row = blockIdx.x * 8 + r;            // flat entity index, 0..8191
        const float* e = emb + (size_t)row * DIN;
        float acc = bias[c];
        #pragma unroll 8
        for (int d = 0; d < DIN; ++d)
            acc += e[d] * Wl[d * COUT + c];
        proj[(size_t)row * COUT + c] = acc;
    } else {
        int i = (blockIdx.x - 1024) * 256 + tid; // 0..8191
        int b = i >> 9;
        int h = loc[2 * i + 0];
        int w = loc[2 * i + 1];
        atomicMax(&cellmap[b * HW + h * WWG + w], i);
    }
}

// ---------------------------------------------------------------------------
// One-pass output build. Grid (64, 49, 16), 256 threads.
//  y in [1,48]: copy spatial channel y-1 (one float4/thread).
//  y == 0:      scatter region — each thread owns 4 pixels x all 32 channels:
//               read int4 of cellmap once, write 32 nontemporal float4 stores
//               (zeros, or gathered proj values for winner pixels).
// ---------------------------------------------------------------------------
__global__ __launch_bounds__(256) void k_build(
        const float* __restrict__ sp, const float* __restrict__ proj,
        const int* __restrict__ cellmap, float* __restrict__ out) {
    int pix4 = blockIdx.x * 256 + threadIdx.x;   // float4 index in image, 0..16383
    int b  = blockIdx.z;
    int y  = blockIdx.y;
    if (y > 0) {
        int ch = y - 1;
        const f4* s = (const f4*)sp + (((size_t)(b * CCS + ch) << 14) + pix4);
        f4 v = __builtin_nontemporal_load(s);
        f4* o = (f4*)out + (((size_t)(b * CTOT + ch) << 14) + pix4);
        __builtin_nontemporal_store(v, o);
        return;
    }
    // scatter region
    int4 cm = ((const int4*)cellmap)[(size_t)b * (HW / 4) + pix4];
    int mx = max(max(cm.x, cm.y), max(cm.z, cm.w));
    f4* obase = (f4*)out + (((size_t)(b * CTOT + CCS) << 14) + pix4);
    if (mx < 0) {
        f4 z = (f4)(0.0f);
        #pragma unroll
        for (int ch = 0; ch < COUT; ++ch)
            __builtin_nontemporal_store(z, obase + ((size_t)ch << 14));
    } else {
        #pragma unroll 4
        for (int ch = 0; ch < COUT; ++ch) {
            f4 v = (f4)(0.0f);
            if (cm.x >= 0) v.x = proj[(size_t)cm.x * COUT + ch];
            if (cm.y >= 0) v.y = proj[(size_t)cm.y * COUT + ch];
            if (cm.z >= 0) v.z = proj[(size_t)cm.z * COUT + ch];
            if (cm.w >= 0) v.w = proj[(size_t)cm.w * COUT + ch];
            __builtin_nontemporal_store(v, obase + ((size_t)ch << 14));
        }
    }
}

extern "C" void kernel_launch(void* const* d_in, const int* in_sizes, int n_in,
                              void* d_out, int out_size, void* d_ws, size_t ws_size,
                              hipStream_t stream) {
    const float* sp   = (const float*)d_in[0];   // [16,48,256,256]
    const float* emb  = (const float*)d_in[1];   // [16,512,256]
    const float* Wm   = (const float*)d_in[2];   // [256,32]
    const float* bias = (const float*)d_in[3];   // [32]
    const int*   loc  = (const int*)d_in[4];     // [16,512,2]
    float* out = (float*)d_out;                  // [16,80,256,256]

    float* proj    = (float*)d_ws;                                     // 1 MB
    int*   cellmap = (int*)((char*)d_ws + (size_t)BB * NN * COUT * 4); // 4 MB

    hipMemsetAsync(cellmap, 0xFF, (size_t)BB * HW * sizeof(int), stream);

    hipLaunchKernelGGL(k_projwin, dim3(1024 + BB * NN / 256), dim3(256), 0, stream,
                       emb, Wm, bias, loc, proj, cellmap);

    hipLaunchKernelGGL(k_build, dim3(HW / 4 / 256, CCS + 1, BB), dim3(256), 0, stream,
                       sp, proj, cellmap, out);
}

// Round 4
// 121.692 us; speedup vs baseline: 1.0392x; 1.0392x over previous
//
#include <hip/hip_runtime.h>

typedef float f4 __attribute__((ext_vector_type(4)));

#define BB   16
#define NN   512
#define DIN  256
#define COUT 32
#define CCS  48
#define HH   256
#define WWG  256
#define HW   (HH * WWG)          // 65536 = 1<<16
#define CTOT (CCS + COUT)        // 80

#define NGEMM   1024             // BB*NN/8 GEMM blocks
#define NWIN    1                // 1 winner block
#define NFILL   (BB * CTOT * 8)  // 10240 fill blocks (8 chunks per channel-image)
#define FILL0   (NGEMM + NWIN)   // first fill block

// ---------------------------------------------------------------------------
// One fused kernel:
//  blocks [0,1024):        proj = emb·W + b   (8 entity-rows/block, W in LDS)
//  block  1024:            winner map: init touched cells to -1, then atomicMax
//                          of flat entity index i (max i == last-write-wins)
//  blocks [1025, 1025+10240): output fill — copy 48 spatial channels, zero the
//                          32 scatter channels. 8 f4 per thread, nontemporal.
// ---------------------------------------------------------------------------
__global__ __launch_bounds__(256) void k_fused(
        const float* __restrict__ emb, const float* __restrict__ Wm,
        const float* __restrict__ bias, const int* __restrict__ loc,
        const float* __restrict__ sp,
        float* __restrict__ proj, int* __restrict__ winner,
        float* __restrict__ out) {
    __shared__ float Wl[DIN * COUT];
    int tid = threadIdx.x;
    int bx  = blockIdx.x;

    if (bx < NGEMM) {
        // ---- proj GEMM ----
        for (int i = tid; i < DIN * COUT; i += 256) Wl[i] = Wm[i];
        __syncthreads();
        int c = tid & 31;
        int r = tid >> 5;                        // 0..7
        int row = bx * 8 + r;                    // flat entity index, 0..8191
        const float* e = emb + (size_t)row * DIN;
        float acc = bias[c];
        #pragma unroll 8
        for (int d = 0; d < DIN; ++d)
            acc += e[d] * Wl[d * COUT + c];      // e[d] uniform broadcast; Wl conflict-free
        proj[(size_t)row * COUT + c] = acc;
        return;
    }
    if (bx == NGEMM) {
        // ---- winner map (single block; only touched cells) ----
        #pragma unroll
        for (int k = 0; k < BB * NN / 256; ++k) {        // 32 iters
            int i = k * 256 + tid;                       // flat entity index
            int b = i >> 9;
            int h = loc[2 * i + 0];
            int w = loc[2 * i + 1];
            winner[b * HW + h * WWG + w] = -1;
        }
        __syncthreads();
        #pragma unroll
        for (int k = 0; k < BB * NN / 256; ++k) {
            int i = k * 256 + tid;
            int b = i >> 9;
            int h = loc[2 * i + 0];
            int w = loc[2 * i + 1];
            atomicMax(&winner[b * HW + h * WWG + w], i);
        }
        return;
    }

    // ---- fill: one block covers a 2048-f4 chunk of one (b, ch) image ----
    int fx    = bx - FILL0;                      // 0..10239
    int chunk = fx & 7;
    int rest  = fx >> 3;                         // 0..1279
    int ch    = rest % CTOT;
    int b     = rest / CTOT;
    size_t o4 = ((size_t)(b * CTOT + ch) << 14) + chunk * 2048 + tid;
    f4* o = (f4*)out + o4;
    if (ch < CCS) {
        const f4* s = (const f4*)sp + (((size_t)(b * CCS + ch) << 14) + chunk * 2048 + tid);
        f4 v[8];
        #pragma unroll
        for (int k = 0; k < 8; ++k) v[k] = __builtin_nontemporal_load(s + k * 256);
        #pragma unroll
        for (int k = 0; k < 8; ++k) __builtin_nontemporal_store(v[k], o + k * 256);
    } else {
        f4 z = (f4)(0.0f);
        #pragma unroll
        for (int k = 0; k < 8; ++k) __builtin_nontemporal_store(z, o + k * 256);
    }
}

// ---------------------------------------------------------------------------
// Winning entity writes its 32-channel proj vector to out[b, 48+c, h, w].
// 32 threads per entity; winner[] read only at touched cells.
// ---------------------------------------------------------------------------
__global__ __launch_bounds__(256) void k_scatter(
        const float* __restrict__ proj, const int* __restrict__ loc,
        const int* __restrict__ winner, float* __restrict__ out) {
    int t = blockIdx.x * 256 + threadIdx.x;
    int c = t & 31;
    int i = t >> 5;                              // flat entity index
    int b = i >> 9;
    int h = loc[2 * i + 0];
    int w = loc[2 * i + 1];
    int cell = b * HW + h * WWG + w;
    if (winner[cell] != i) return;               // last-write-wins (max flat index)
    out[((size_t)(b * CTOT + CCS + c) << 16) + (size_t)h * WWG + w] =
        proj[(size_t)i * COUT + c];
}

extern "C" void kernel_launch(void* const* d_in, const int* in_sizes, int n_in,
                              void* d_out, int out_size, void* d_ws, size_t ws_size,
                              hipStream_t stream) {
    const float* sp   = (const float*)d_in[0];   // [16,48,256,256]
    const float* emb  = (const float*)d_in[1];   // [16,512,256]
    const float* Wm   = (const float*)d_in[2];   // [256,32]
    const float* bias = (const float*)d_in[3];   // [32]
    const int*   loc  = (const int*)d_in[4];     // [16,512,2]
    float* out = (float*)d_out;                  // [16,80,256,256]

    float* proj   = (float*)d_ws;                                     // 1 MB
    int*   winner = (int*)((char*)d_ws + (size_t)BB * NN * COUT * 4); // 4 MB

    hipLaunchKernelGGL(k_fused, dim3(NGEMM + NWIN + NFILL), dim3(256), 0, stream,
                       emb, Wm, bias, loc, sp, proj, winner, out);

    hipLaunchKernelGGL(k_scatter, dim3(BB * NN * COUT / 256), dim3(256), 0, stream,
                       proj, loc, winner, out);
}